// Round 10
// baseline (69.572 us; speedup 1.0000x reference)
//
#include <hip/hip_runtime.h>

// DropBlock, N=64 C=64 H=80 W=80, block_size=5 (top/left-clipped window max).
// R10: thread-per-row mask kernel. Lane l owns row l: 20 int4 loads (2x10
// bursts), pack 80 bits into 3 regs (no cross-lane), width-5 row-OR in regs,
// col-OR via 4 __shfl's/word from neighbor lanes. Zero LDS, zero barriers,
// wave = plane. Pass B (rows 60-79, lanes 0-19) re-loads 4 halo rows (+5%).
// Mask stored as uint4/row (coalesced). Apply uses consecutive-bit layout.
// Lessons kept: no atomics (R3), no memset in graph (R4), no grid.sync (R8),
// coalesce+redistribute variants all plateau ~29us (R7/R9) -> try scatter.
#define DB_H 80
#define DB_W 80
#define DB_PLANE (DB_H * DB_W)               // 6400
#define DB_NPLANES 4096                      // N*C
#define DB_TOTAL (DB_PLANE * DB_NPLANES)     // 26214400
#define DB_COUNT_F 26214400.0f               // 25 * 2^20 — exact in f32
#define DB_CNT_BYTES (DB_NPLANES * 4)        // 16384
#define DB_BP_UINT4 (DB_NPLANES * DB_H)      // 327680 uint4 = 5.24 MB
#define WPB 4

// Kernel 1: wave = plane; thread = row. Window-OR + zero count + mask store.
__global__ __launch_bounds__(256, 4) void db_mask_rows(
    const int4* __restrict__ mask4,
    uint4* __restrict__ bp,                  // [plane][row] = {c0,c1,c2,0}
    unsigned int* __restrict__ counts)
{
    const int wid = threadIdx.x >> 6, lane = threadIdx.x & 63;
    const int plane = blockIdx.x * WPB + wid;
    const int4* mp = mask4 + (size_t)plane * 1600;   // 20 int4 per row

    unsigned int zeros = 0;

    // ---------------- Pass A: rows 0-63 (lane l = row l) ----------------
    {
        const int4* rp = mp + lane * 20;
        unsigned b0 = 0, b1 = 0, b2 = 0;
        int4 v[10];
        #pragma unroll
        for (int k = 0; k < 10; ++k) v[k] = rp[k];
        #pragma unroll
        for (int k = 0; k < 10; ++k) {
            const unsigned nib = (unsigned)(v[k].x & 1) |
                                 ((unsigned)(v[k].y & 1) << 1) |
                                 ((unsigned)(v[k].z & 1) << 2) |
                                 ((unsigned)(v[k].w & 1) << 3);
            if (k < 8) b0 |= nib << (k * 4);
            else       b1 |= nib << ((k - 8) * 4);
        }
        #pragma unroll
        for (int k = 0; k < 10; ++k) v[k] = rp[10 + k];
        #pragma unroll
        for (int k = 0; k < 10; ++k) {
            const int kk = 10 + k;
            const unsigned nib = (unsigned)(v[k].x & 1) |
                                 ((unsigned)(v[k].y & 1) << 1) |
                                 ((unsigned)(v[k].z & 1) << 2) |
                                 ((unsigned)(v[k].w & 1) << 3);
            if (kk < 16) b1 |= nib << ((kk - 8) * 4);
            else         b2 |= nib << ((kk - 16) * 4);
        }
        // Width-5 left-clipped sliding OR: r = OR_{s=0..4} b<<s (96-bit).
        unsigned r0 = b0, r1 = b1, r2 = b2;
        #pragma unroll
        for (int s = 1; s <= 4; ++s) {
            r0 |= b0 << s;
            r1 |= (b1 << s) | (b0 >> (32 - s));
            r2 |= (b2 << s) | (b1 >> (32 - s));
        }
        r2 &= 0xFFFFu;
        // Col OR over rows i-4..i via lane shuffles (top clip by guard).
        unsigned c0 = r0, c1 = r1, c2 = r2;
        #pragma unroll
        for (int k = 1; k <= 4; ++k) {
            const int src = (lane >= k) ? (lane - k) : 0;
            const unsigned s0 = (unsigned)__shfl((int)r0, src, 64);
            const unsigned s1 = (unsigned)__shfl((int)r1, src, 64);
            const unsigned s2 = (unsigned)__shfl((int)r2, src, 64);
            if (lane >= k) { c0 |= s0; c1 |= s1; c2 |= s2; }
        }
        zeros += 80u - __popc(c0) - __popc(c1) - __popc(c2);
        bp[(size_t)plane * DB_H + lane] = make_uint4(c0, c1, c2, 0u);
    }

    // ------- Pass B: rows 60-79 on lanes 0-19 (outputs rows 64-79) -------
    if (lane < 20) {
        const int row = 60 + lane;
        const int4* rp = mp + row * 20;
        unsigned b0 = 0, b1 = 0, b2 = 0;
        int4 v[10];
        #pragma unroll
        for (int k = 0; k < 10; ++k) v[k] = rp[k];
        #pragma unroll
        for (int k = 0; k < 10; ++k) {
            const unsigned nib = (unsigned)(v[k].x & 1) |
                                 ((unsigned)(v[k].y & 1) << 1) |
                                 ((unsigned)(v[k].z & 1) << 2) |
                                 ((unsigned)(v[k].w & 1) << 3);
            if (k < 8) b0 |= nib << (k * 4);
            else       b1 |= nib << ((k - 8) * 4);
        }
        #pragma unroll
        for (int k = 0; k < 10; ++k) v[k] = rp[10 + k];
        #pragma unroll
        for (int k = 0; k < 10; ++k) {
            const int kk = 10 + k;
            const unsigned nib = (unsigned)(v[k].x & 1) |
                                 ((unsigned)(v[k].y & 1) << 1) |
                                 ((unsigned)(v[k].z & 1) << 2) |
                                 ((unsigned)(v[k].w & 1) << 3);
            if (kk < 16) b1 |= nib << ((kk - 8) * 4);
            else         b2 |= nib << ((kk - 16) * 4);
        }
        unsigned r0 = b0, r1 = b1, r2 = b2;
        #pragma unroll
        for (int s = 1; s <= 4; ++s) {
            r0 |= b0 << s;
            r1 |= (b1 << s) | (b0 >> (32 - s));
            r2 |= (b2 << s) | (b1 >> (32 - s));
        }
        r2 &= 0xFFFFu;
        // Col OR: lane l (>=4) outputs row 64+(l-4); sources l-4..l all <20.
        unsigned c0 = r0, c1 = r1, c2 = r2;
        #pragma unroll
        for (int k = 1; k <= 4; ++k) {
            const unsigned s0 = (unsigned)__shfl((int)r0, lane - k, 64);
            const unsigned s1 = (unsigned)__shfl((int)r1, lane - k, 64);
            const unsigned s2 = (unsigned)__shfl((int)r2, lane - k, 64);
            if (lane >= k) { c0 |= s0; c1 |= s1; c2 |= s2; }
        }
        if (lane >= 4) {
            zeros += 80u - __popc(c0) - __popc(c1) - __popc(c2);
            bp[(size_t)plane * DB_H + row] = make_uint4(c0, c1, c2, 0u);
        }
    }

    // Wave reduce + one plain store per plane (no init needed).
    for (int off = 32; off > 0; off >>= 1)
        zeros += (unsigned int)__shfl_down((int)zeros, off, 64);
    if (lane == 0) counts[plane] = zeros;
}

// Kernel 2: out = blocked ? 0 : x * (countM / count_zeros), float4 stream.
// Prologue: block-local sum of 4096 per-plane counts (16KB, L3-resident).
__global__ __launch_bounds__(256) void db_apply_bits(
    const float4* __restrict__ x,
    const uint4* __restrict__ bp,
    const unsigned int* __restrict__ counts,
    float4* __restrict__ out)
{
    __shared__ float s_scale;
    __shared__ unsigned int s_part[4];
    {
        const uint4* cp = (const uint4*)counts;   // 1024 uint4
        unsigned int c = 0;
        #pragma unroll
        for (int k = 0; k < 4; ++k) {
            uint4 v = cp[k * 256 + threadIdx.x];
            c += v.x + v.y + v.z + v.w;
        }
        for (int off = 32; off > 0; off >>= 1)
            c += (unsigned int)__shfl_down((int)c, off, 64);
        if ((threadIdx.x & 63) == 0) s_part[threadIdx.x >> 6] = c;
        __syncthreads();
        if (threadIdx.x == 0)
            s_scale = DB_COUNT_F /
                      (float)(s_part[0] + s_part[1] + s_part[2] + s_part[3]);
        __syncthreads();
    }
    const float scale = s_scale;
    const unsigned NG = DB_TOTAL / 4;             // 6553600 float4s
    const unsigned stride = gridDim.x * blockDim.x;
    #pragma unroll 2
    for (unsigned g = blockIdx.x * blockDim.x + threadIdx.x; g < NG; g += stride) {
        const unsigned plane = g / 1600u;
        const unsigned gp = g - plane * 1600u;
        const unsigned i = gp / 20u;              // row
        const unsigned q = gp - i * 20u;          // quad index in row (0..19)
        const uint4 b = bp[plane * DB_H + i];
        const unsigned word = (q < 8u) ? b.x : ((q < 16u) ? b.y : b.z);
        const unsigned nib = (word >> ((q & 7u) * 4u)) & 0xFu;
        float4 v = make_float4(0.f, 0.f, 0.f, 0.f);
        if (nib != 0xFu) v = x[g];
        float4 o;
        o.x = (nib & 1u) ? 0.0f : v.x * scale;
        o.y = (nib & 2u) ? 0.0f : v.y * scale;
        o.z = (nib & 4u) ? 0.0f : v.z * scale;
        o.w = (nib & 8u) ? 0.0f : v.w * scale;
        out[g] = o;
    }
}

// ---- Fallback (ws too small): R7-style recompute path, known-good. ----
__global__ __launch_bounds__(256) void db_count_kernel(
    const int* __restrict__ mask,
    unsigned int* __restrict__ counts)
{
    __shared__ unsigned long long P[WPB][104];
    __shared__ unsigned int RO[WPB][DB_H * 3];
    const int wid = threadIdx.x >> 6, lane = threadIdx.x & 63;
    const int plane = blockIdx.x * WPB + wid;
    const int* mp = mask + plane * DB_PLANE;
    unsigned long long* Pp = P[wid];
    unsigned int* ro = RO[wid];
    #pragma unroll 1
    for (int c = 0; c < 10; ++c) {
        int v[10];
        #pragma unroll
        for (int k = 0; k < 10; ++k) v[k] = mp[(c * 10 + k) * 64 + lane];
        #pragma unroll
        for (int k = 0; k < 10; ++k) {
            unsigned long long bal = __ballot(v[k] & 1);
            if (lane == 0) Pp[c * 10 + k] = bal;
        }
    }
    if (lane < 4) Pp[100 + lane] = 0ULL;
    __syncthreads();
    for (int r = lane; r < DB_H; r += 64) {
        const int bitpos = r * DB_W;
        const int q = bitpos >> 6, off = bitpos & 63;
        unsigned long long a, b;
        if (off) {
            a = (Pp[q] >> off) | (Pp[q + 1] << (64 - off));
            b = (Pp[q + 1] >> off) | (Pp[q + 2] << (64 - off));
        } else {
            a = Pp[q]; b = Pp[q + 1];
        }
        b &= 0xFFFFULL;
        unsigned long long ra = a, rb = b;
        #pragma unroll
        for (int s = 1; s <= 4; ++s) {
            ra |= a << s;
            rb |= (b << s) | (a >> (64 - s));
        }
        rb &= 0xFFFFULL;
        ro[r * 3 + 0] = (unsigned int)ra;
        ro[r * 3 + 1] = (unsigned int)(ra >> 32);
        ro[r * 3 + 2] = (unsigned int)rb;
    }
    __syncthreads();
    unsigned int zeros = 0;
    for (int i = lane; i < DB_H; i += 64) {
        const int lo = (i >= 4) ? i - 4 : 0;
        unsigned int c0 = 0, c1 = 0, c2 = 0;
        for (int ii = lo; ii <= i; ++ii) {
            c0 |= ro[ii * 3 + 0];
            c1 |= ro[ii * 3 + 1];
            c2 |= ro[ii * 3 + 2];
        }
        zeros += 80u - __popc(c0) - __popc(c1) - __popc(c2);
    }
    for (int off = 32; off > 0; off >>= 1)
        zeros += (unsigned int)__shfl_down((int)zeros, off, 64);
    if (lane == 0) counts[plane] = zeros;
}

__global__ __launch_bounds__(256) void db_apply_recompute(
    const float* __restrict__ x,
    const int* __restrict__ mask,
    const unsigned int* __restrict__ counts,
    float* __restrict__ out)
{
    __shared__ unsigned long long P[WPB][104];
    __shared__ unsigned int RO[WPB][DB_H * 3];
    __shared__ unsigned int BM[WPB][DB_H * 3];
    __shared__ float s_scale;
    __shared__ unsigned int s_part[4];
    {
        const uint4* cp = (const uint4*)counts;
        unsigned int c = 0;
        #pragma unroll
        for (int k = 0; k < 4; ++k) {
            uint4 v = cp[k * 256 + threadIdx.x];
            c += v.x + v.y + v.z + v.w;
        }
        for (int off = 32; off > 0; off >>= 1)
            c += (unsigned int)__shfl_down((int)c, off, 64);
        if ((threadIdx.x & 63) == 0) s_part[threadIdx.x >> 6] = c;
        __syncthreads();
        if (threadIdx.x == 0)
            s_scale = DB_COUNT_F /
                      (float)(s_part[0] + s_part[1] + s_part[2] + s_part[3]);
        __syncthreads();
    }
    const float scale = s_scale;
    const int wid = threadIdx.x >> 6, lane = threadIdx.x & 63;
    const int plane = blockIdx.x * WPB + wid;
    const int* mp = mask + plane * DB_PLANE;
    unsigned long long* Pp = P[wid];
    unsigned int* ro = RO[wid];
    #pragma unroll 1
    for (int c = 0; c < 10; ++c) {
        int v[10];
        #pragma unroll
        for (int k = 0; k < 10; ++k) v[k] = mp[(c * 10 + k) * 64 + lane];
        #pragma unroll
        for (int k = 0; k < 10; ++k) {
            unsigned long long bal = __ballot(v[k] & 1);
            if (lane == 0) Pp[c * 10 + k] = bal;
        }
    }
    if (lane < 4) Pp[100 + lane] = 0ULL;
    __syncthreads();
    for (int r = lane; r < DB_H; r += 64) {
        const int bitpos = r * DB_W;
        const int q = bitpos >> 6, off = bitpos & 63;
        unsigned long long a, b;
        if (off) {
            a = (Pp[q] >> off) | (Pp[q + 1] << (64 - off));
            b = (Pp[q + 1] >> off) | (Pp[q + 2] << (64 - off));
        } else {
            a = Pp[q]; b = Pp[q + 1];
        }
        b &= 0xFFFFULL;
        unsigned long long ra = a, rb = b;
        #pragma unroll
        for (int s = 1; s <= 4; ++s) {
            ra |= a << s;
            rb |= (b << s) | (a >> (64 - s));
        }
        rb &= 0xFFFFULL;
        ro[r * 3 + 0] = (unsigned int)ra;
        ro[r * 3 + 1] = (unsigned int)(ra >> 32);
        ro[r * 3 + 2] = (unsigned int)rb;
    }
    __syncthreads();
    unsigned int* bmp = BM[wid];
    for (int i = lane; i < DB_H; i += 64) {
        const int lo = (i >= 4) ? i - 4 : 0;
        unsigned int c0 = 0, c1 = 0, c2 = 0;
        for (int ii = lo; ii <= i; ++ii) {
            c0 |= ro[ii * 3 + 0];
            c1 |= ro[ii * 3 + 1];
            c2 |= ro[ii * 3 + 2];
        }
        bmp[i * 3 + 0] = c0; bmp[i * 3 + 1] = c1; bmp[i * 3 + 2] = c2;
    }
    __syncthreads();
    const float* xp = x + plane * DB_PLANE;
    float* op = out + plane * DB_PLANE;
    for (int e = lane; e < DB_PLANE; e += 64) {
        int i = e / DB_W, j = e - i * DB_W;
        unsigned int wb = bmp[i * 3 + (j >> 5)] >> (j & 31);
        op[e] = (wb & 1u) ? 0.0f : xp[e] * scale;
    }
}

extern "C" void kernel_launch(void* const* d_in, const int* in_sizes, int n_in,
                              void* d_out, int out_size, void* d_ws, size_t ws_size,
                              hipStream_t stream) {
    const float* x = (const float*)d_in[0];
    const int* mask = (const int*)d_in[1];
    float* out = (float*)d_out;

    unsigned int* counts = (unsigned int*)d_ws;
    uint4* bp = (uint4*)((char*)d_ws + DB_CNT_BYTES);
    const size_t need = DB_CNT_BYTES + (size_t)DB_BP_UINT4 * sizeof(uint4);

    if (ws_size >= need) {
        db_mask_rows<<<DB_NPLANES / WPB, 256, 0, stream>>>(
            (const int4*)mask, bp, counts);
        db_apply_bits<<<2048, 256, 0, stream>>>(
            (const float4*)x, bp, counts, (float4*)out);
    } else {
        db_count_kernel<<<DB_NPLANES / WPB, 256, 0, stream>>>(mask, counts);
        db_apply_recompute<<<DB_NPLANES / WPB, 256, 0, stream>>>(
            x, mask, counts, out);
    }
}